// Round 14
// baseline (693.188 us; speedup 1.0000x reference)
//
#include <hip/hip_runtime.h>

// ---------------------------------------------------------------------------
// ParC-ConvNeXt block, MI355X (gfx950).
//   out = x + gamma * MLP(LN(NHWC(concat(ParC_H(x[:192]), ParC_W(x[192:])))))
// Round 13 -> 14: weights-from-L2 GEMM. A (W1P/W2P, 590KB L2-resident) is
//   no longer staged through LDS: per-wave global->register loads (4x
//   dwordx4 at imm offsets, 1-step reg double-buffer). LDS now holds only
//   B (activations): R = LDS-reads/MFMA 2 -> 1 (LDS 576 < MFMA 828 cyc/CU
//   -> matrix pipe finally binding). Slots halve: GEMM1 48KB, GEMM2 24KB.
//   Counted vmcnt schedule: issue A(t+1) then stageB(t+2); wait vmcnt(2).
//   pack merged into conv launch. Everything else unchanged.
// ---------------------------------------------------------------------------

typedef __attribute__((ext_vector_type(8))) short short8;
typedef __attribute__((ext_vector_type(4))) float f32x4;
typedef __attribute__((ext_vector_type(16))) float f32x16;
typedef __attribute__((ext_vector_type(4))) int int4v;
typedef __attribute__((ext_vector_type(8))) int i32x8;

__device__ __forceinline__ float bf2f(unsigned short u) {
  union { unsigned int i; float f; } v; v.i = ((unsigned int)u) << 16; return v.f;
}
__device__ __forceinline__ unsigned short f2bf(float f) {
  union { float f; unsigned int i; } v; v.f = f;
  unsigned int r = v.i + 0x7FFFu + ((v.i >> 16) & 1u);
  return (unsigned short)(r >> 16);
}

#if defined(__has_builtin)
#if __has_builtin(__builtin_amdgcn_global_load_lds)
#define HAS_GLL 1
#endif
#endif
#ifndef HAS_GLL
#define HAS_GLL 0
#endif

#if HAS_GLL
__device__ __forceinline__ void gload16(const void* g, void* l) {
  __builtin_amdgcn_global_load_lds((const __attribute__((address_space(1))) void*)g,
                                   (__attribute__((address_space(3))) void*)l, 16, 0, 0);
}
#else
__device__ __forceinline__ void gload16(const void* g, void* l) {
  *(f32x4*)l = *(const f32x4*)g;
}
#endif

template <int N>
__device__ __forceinline__ void wait_vm() {
  asm volatile("s_waitcnt vmcnt(%0)" :: "n"(N) : "memory");
}
__device__ __forceinline__ void barrier_raw() {
  __builtin_amdgcn_s_barrier();
  __builtin_amdgcn_sched_barrier(0);
}

// fast sigmoid-GELU: h * sigmoid(1.702h); exp2/rcp HW approx (1e-6 slack)
__device__ __forceinline__ float fast_gelu(float h) {
  const float e = __builtin_amdgcn_exp2f(-2.4554005f * h);  // 1.702/ln2 folded
  return h * __builtin_amdgcn_rcpf(1.f + e);
}

// pack 4 consecutive-k f32 into fp8 dword
__device__ __forceinline__ int pk4(float a, float b, float c, float d) {
  int r = __builtin_amdgcn_cvt_pk_fp8_f32(a, b, 0, false);
  return __builtin_amdgcn_cvt_pk_fp8_f32(c, d, r, true);
}

#define SCL1 0x7F7F7F7F  // E8M0 = 127 -> 2^0 in all 4 bytes

// Packed fragment layout (per kt): byte offset for (row, 16B-k-chunk kc):
//   (row>>5)*2048 + (kc&1)*1024 + (kc>>1)*512 + (row&31)*16
__device__ __forceinline__ int packed_off(int row, int kc) {
  return ((row >> 5) << 11) + ((kc & 1) << 10) + ((kc >> 1) << 9) + ((row & 31) << 4);
}

// --------------------- fused weight-pack + ParC conv -----------------------
// blocks 0..35:  w1 -> W1P [kt 6][packed h 1536];  36..59: w2 -> W2P [kt 24]
// blocks 60..1595: ParC conv (bid-60), writes CONV bf16 NCHW.
__global__ __launch_bounds__(256) void prep_kernel(
    const float* __restrict__ w1, const float* __restrict__ w2,
    char* __restrict__ w1p, char* __restrict__ w2p,
    const float* __restrict__ x,
    const float* __restrict__ pe_h, const float* __restrict__ w_h, const float* __restrict__ b_h,
    const float* __restrict__ pe_w, const float* __restrict__ w_w, const float* __restrict__ b_w,
    unsigned short* __restrict__ convout) {
  const int t = threadIdx.x;
  int bid = blockIdx.x;
  if (bid < 60) {
    float v[64];
    if (bid < 36) {
      const int kt = bid % 6, hg = bid / 6;
      const int h = hg * 256 + t;
      #pragma unroll
      for (int k = 0; k < 64; ++k) v[k] = w1[(size_t)(kt * 64 + k) * 1536 + h];
      char* base = w1p + (size_t)kt * 1536 * 64;
      #pragma unroll
      for (int k0 = 0; k0 < 64; k0 += 4)
        *(int*)(base + packed_off(h, k0 >> 4) + (k0 & 12)) =
            pk4(v[k0], v[k0 + 1], v[k0 + 2], v[k0 + 3]);
    } else {
      const int kt = bid - 36;
      for (int c = t; c < 384; c += 256) {
        #pragma unroll
        for (int k = 0; k < 64; ++k) v[k] = w2[(size_t)(kt * 64 + k) * 384 + c];
        char* base = w2p + (size_t)kt * 384 * 64;
        #pragma unroll
        for (int k0 = 0; k0 < 64; k0 += 4)
          *(int*)(base + packed_off(c, k0 >> 4) + (k0 & 12)) =
              pk4(v[k0], v[k0 + 1], v[k0 + 2], v[k0 + 3]);
      }
    }
    return;
  }
  bid -= 60;
  __shared__ float wt_s[8][32], pe_s[8][32], pc_s[8][32];
  const int b = bid / 48, g = bid % 48;
  const int c0 = g << 3;
  const bool ish = (c0 < 192);
  const int cl = t >> 5, q = t & 31;
  {
    const int c = c0 + cl;
    if (ish) { wt_s[cl][q] = w_h[(c << 5) + q];           pe_s[cl][q] = pe_h[(c << 5) + q]; }
    else     { const int cc = c - 192;
               wt_s[cl][q] = w_w[(cc << 5) + q];          pe_s[cl][q] = pe_w[(cc << 5) + q]; }
  }
  __syncthreads();
  {
    float s = ish ? b_h[c0 + cl] : b_w[c0 + cl - 192];
    #pragma unroll
    for (int i = 0; i < 32; ++i) s += pe_s[cl][(q + i) & 31] * wt_s[cl][i];
    pc_s[cl][q] = s;
  }
  __syncthreads();
  const float* xp = x + ((size_t)(b * 384 + c0 + cl) << 10);
  float col[32];
  if (ish) {
    #pragma unroll
    for (int j = 0; j < 32; ++j) col[j] = xp[(j << 5) + q];
  } else {
    const float* rp = xp + (q << 5);
    #pragma unroll
    for (int j4 = 0; j4 < 8; ++j4) {
      f32x4 v = *(const f32x4*)&rp[j4 << 2];
      col[j4 * 4 + 0] = v[0]; col[j4 * 4 + 1] = v[1];
      col[j4 * 4 + 2] = v[2]; col[j4 * 4 + 3] = v[3];
    }
  }
  float wr[32];
  #pragma unroll
  for (int i = 0; i < 32; ++i) wr[i] = wt_s[cl][i];
  float o[32];
  #pragma unroll
  for (int oo = 0; oo < 32; ++oo) o[oo] = pc_s[cl][oo];
  #pragma unroll
  for (int i = 0; i < 32; ++i)
    #pragma unroll
    for (int oo = 0; oo < 32; ++oo)
      o[oo] = fmaf(col[(oo + i) & 31], wr[i], o[oo]);
  unsigned short* op = convout + ((size_t)(b * 384 + c0 + cl) << 10);
  if (ish) {
    #pragma unroll
    for (int oo = 0; oo < 32; ++oo) op[(oo << 5) + q] = f2bf(o[oo]);
  } else {
    #pragma unroll
    for (int j8 = 0; j8 < 4; ++j8) {
      short8 p;
      #pragma unroll
      for (int j = 0; j < 8; ++j) p[j] = (short)f2bf(o[j8 * 8 + j]);
      *(short8*)&op[(q << 5) + j8 * 8] = p;
    }
  }
}

// --------------------------- fused LayerNorm -------------------------------
__global__ __launch_bounds__(256) void ln_fused_kernel(
    const unsigned short* __restrict__ conv, char* __restrict__ ylnp,
    const float* __restrict__ ln_w, const float* __restrict__ ln_b) {
  __shared__ unsigned short tile[384][72];   // 55296 B (144B pitch, bank-safe)
  __shared__ float lws[384], lbs[384];
  __shared__ float ps[4][64], pq[4][64];
  __shared__ float mus[64], rss[64];
  const int t = threadIdx.x;
  const int pb = blockIdx.x;
  const int b = pb >> 4;
  const int hw0 = (pb & 15) << 6;
  for (int i = t; i < 384; i += 256) { lws[i] = ln_w[i]; lbs[i] = ln_b[i]; }
  #pragma unroll
  for (int i = 0; i < 12; ++i) {
    const int idx = t + i * 256;
    const int c = idx >> 3, j = idx & 7;
    short8 v = *(const short8*)(conv + (((size_t)(b * 384 + c)) << 10) + hw0 + j * 8);
    *(short8*)&tile[c][j * 8] = v;
  }
  __syncthreads();
  {
    const int l = t & 63, qt = t >> 6;
    float s = 0.f, ss = 0.f;
    #pragma unroll
    for (int k = 0; k < 96; ++k) {
      const float v = bf2f(tile[qt * 96 + k][l]);
      s += v; ss = fmaf(v, v, ss);
    }
    ps[qt][l] = s; pq[qt][l] = ss;
  }
  __syncthreads();
  if (t < 64) {
    const float st = ps[0][t] + ps[1][t] + ps[2][t] + ps[3][t];
    const float sq = pq[0][t] + pq[1][t] + pq[2][t] + pq[3][t];
    const float m = st * (1.f / 384.f);
    const float var = sq * (1.f / 384.f) - m * m;
    mus[t] = m; rss[t] = rsqrtf(var + 1e-6f);
  }
  __syncthreads();
  const int l = t & 63, kc = t >> 6;
  const int px = pb * 64 + l;
  const float m = mus[l], r = rss[l];
  #pragma unroll
  for (int kt = 0; kt < 6; ++kt) {
    const int c0 = kt * 64 + kc * 16;
    float ov[16];
    #pragma unroll
    for (int e = 0; e < 16; ++e) {
      const float v = bf2f(tile[c0 + e][l]);
      ov[e] = (v - m) * r * lws[c0 + e] + lbs[c0 + e];
    }
    int4v d;
    d[0] = pk4(ov[0],  ov[1],  ov[2],  ov[3]);
    d[1] = pk4(ov[4],  ov[5],  ov[6],  ov[7]);
    d[2] = pk4(ov[8],  ov[9],  ov[10], ov[11]);
    d[3] = pk4(ov[12], ov[13], ov[14], ov[15]);
    *(int4v*)(ylnp + (size_t)kt * 32768 * 64 + packed_off(px, kc)) = d;
  }
}

// --------------------------- GEMM (MX fp8) ---------------------------------
// A (weights) from global/L2 -> registers (1-step reg double-buffer);
// B (activations) via gload_lds ring (NB=3, DEPTH=2, counted vmcnt).
// Wave tile 64x64 (acc f32x16[2][2]); NWM=2 x NWN waves; BM=128, BN=NWN*64.
// Per step per wave: 4 global A loads + 4 ds_read_b128 (R=1) + 4 MFMA.
// EPI 0 (GEMM1, NWN=4): HID fp8 [kt 24][packed px hstride], gelu+pk4.
// EPI 1 (GEMM2, NWN=2): out(NCHW f32) = x + gamma*(acc+b2).
template <int EPI, int KDIM, int AROWS, int NWN>
__global__ __launch_bounds__(NWN * 128, 6) void gemm_kernel(
    const char* __restrict__ Ab, const char* __restrict__ Bb,
    char* __restrict__ Hout8, const float* __restrict__ bias,
    const float* __restrict__ gamma, const float* __restrict__ xres,
    float* __restrict__ out, int px0, int bstride, int boff, int hstride,
    int nwg, int nx) {
  extern __shared__ char lds[];
  constexpr int BM = 128;
  constexpr int BN = NWN * 64;
  constexpr int THREADS = NWN * 128;
  constexpr int NB = 3;
  constexpr int NT = KDIM / 64;
  constexpr int SLOT = BN * 64;
  constexpr int BCH = BN * 4 / THREADS;      // = 2 for both configs
  static_assert(BCH == 2, "vmcnt schedule assumes 2 B-ops/thread");
  const int tid = threadIdx.x;
  const int lane = tid & 63;
  const int wid = tid >> 6;
  const int wm = wid / NWN;                  // 0..1: A 64-row half
  const int wn = wid % NWN;                  // B 64-px group
  const int lane31 = lane & 31;
  const int kh = lane >> 5;
  const int bid = blockIdx.x;
  const int q = nwg >> 3, r = nwg & 7;
  const int xcd = bid & 7, idx = bid >> 3;
  const int lg = (xcd < r ? xcd * (q + 1) : r * (q + 1) + (xcd - r) * q) + idx;
  const int xb = lg % nx, yb = lg / nx;
  const int arow0 = xb * BM;
  const int brow0 = yb * BN;

  f32x16 acc[2][2] = {};

  // per-thread A global base (weights, packed layout; frags at +0/1024/2048/3072)
  const char* aglob = Ab + ((size_t)(arow0 + wm * 64)) * 64 + (kh << 9) + (lane31 << 4);
  int bbase[2];
  #pragma unroll
  for (int n = 0; n < 2; ++n)
    bbase[n] = ((wn * 2 + n) << 11) + (kh << 9) + (lane31 << 4);

  auto stageB = [&](int tile) {
    char* sl = lds + (tile % NB) * SLOT;
    const char* bsrc = Bb + ((size_t)tile * bstride + boff + brow0) * 64;
    #pragma unroll
    for (int i = 0; i < BCH; ++i)
      gload16(bsrc + (i * THREADS + tid) * 16, sl + (i * THREADS + tid) * 16);
  };
  auto loadA = [&](int t, i32x8& f0, i32x8& f1) {
    const char* p = aglob + (size_t)t * (size_t)(AROWS * 64);
    int4v q0 = *(const int4v*)(p);
    int4v q1 = *(const int4v*)(p + 1024);
    int4v q2 = *(const int4v*)(p + 2048);
    int4v q3 = *(const int4v*)(p + 3072);
    f0[0]=q0[0]; f0[1]=q0[1]; f0[2]=q0[2]; f0[3]=q0[3];
    f0[4]=q1[0]; f0[5]=q1[1]; f0[6]=q1[2]; f0[7]=q1[3];
    f1[0]=q2[0]; f1[1]=q2[1]; f1[2]=q2[2]; f1[3]=q2[3];
    f1[4]=q3[0]; f1[5]=q3[1]; f1[6]=q3[2]; f1[7]=q3[3];
  };
  auto readB = [&](int t, i32x8 bv[2]) {
    const char* slp = lds + (t % NB) * SLOT;
    #pragma unroll
    for (int n = 0; n < 2; ++n) {
      int4v p0 = *(const int4v*)(slp + bbase[n]);
      int4v p1 = *(const int4v*)(slp + bbase[n] + 1024);
      bv[n][0]=p0[0]; bv[n][1]=p0[1]; bv[n][2]=p0[2]; bv[n][3]=p0[3];
      bv[n][4]=p1[0]; bv[n][5]=p1[1]; bv[n][6]=p1[2]; bv[n][7]=p1[3];
    }
  };
  auto mfma4 = [&](i32x8& a0, i32x8& a1, i32x8 bv[2]) {
    __builtin_amdgcn_s_setprio(1);
    acc[0][0] = __builtin_amdgcn_mfma_scale_f32_32x32x64_f8f6f4(
        a0, bv[0], acc[0][0], 0, 0, 0, SCL1, 0, SCL1);
    acc[0][1] = __builtin_amdgcn_mfma_scale_f32_32x32x64_f8f6f4(
        a0, bv[1], acc[0][1], 0, 0, 0, SCL1, 0, SCL1);
    acc[1][0] = __builtin_amdgcn_mfma_scale_f32_32x32x64_f8f6f4(
        a1, bv[0], acc[1][0], 0, 0, 0, SCL1, 0, SCL1);
    acc[1][1] = __builtin_amdgcn_mfma_scale_f32_32x32x64_f8f6f4(
        a1, bv[1], acc[1][1], 0, 0, 0, SCL1, 0, SCL1);
    __builtin_amdgcn_s_setprio(0);
  };

  i32x8 aA0, aA1, aB0, aB1;
  // prologue: A(0) first, then B(0), B(1) -> wait vmcnt(2) leaves B(1) in flight
  loadA(0, aA0, aA1);
  stageB(0);
  stageB(1);
  wait_vm<2>();
  barrier_raw();

  int t = 0;
  #pragma unroll 1
  for (; t + 3 < NT; t += 2) {
    {
      i32x8 bv[2]; readB(t, bv);
      loadA(t + 1, aB0, aB1);
      stageB(t + 2);
      mfma4(aA0, aA1, bv);
      wait_vm<2>();           // A(t+1) + B(t+1) landed; B(t+2) in flight
      barrier_raw();
    }
    {
      i32x8 bv[2]; readB(t + 1, bv);
      loadA(t + 2, aA0, aA1);
      stageB(t + 3);
      mfma4(aB0, aB1, bv);
      wait_vm<2>();
      barrier_raw();
    }
  }
  // peeled final pair (t == NT-2)
  {
    i32x8 bv[2]; readB(t, bv);
    loadA(t + 1, aB0, aB1);
    mfma4(aA0, aA1, bv);
    wait_vm<0>();
    barrier_raw();
  }
  {
    i32x8 bv[2]; readB(t + 1, bv);
    mfma4(aB0, aB1, bv);
  }

  // D (32x32 frag): col = lane31, row = (reg&3) + 8*(reg>>2) + 4*kh
  if (EPI == 0) {
    #pragma unroll
    for (int fm = 0; fm < 2; ++fm) {
      const int wmf = wm * 2 + fm;
      const int kt2 = (arow0 >> 6) + (wmf >> 1);
      #pragma unroll
      for (int G = 0; G < 4; ++G) {
        const int hbyte = ((wmf & 1) << 5) + 8 * G + 4 * kh;
        const int hglob = arow0 + (wmf << 5) + 8 * G + 4 * kh;
        const float c0 = bias[hglob + 0], c1 = bias[hglob + 1];
        const float c2 = bias[hglob + 2], c3 = bias[hglob + 3];
        const int kc = hbyte >> 4, sub = hbyte & 15;
        #pragma unroll
        for (int n = 0; n < 2; ++n) {
          const int px = brow0 + wn * 64 + n * 32 + lane31;
          const int d = pk4(fast_gelu(acc[fm][n][4 * G + 0] + c0),
                            fast_gelu(acc[fm][n][4 * G + 1] + c1),
                            fast_gelu(acc[fm][n][4 * G + 2] + c2),
                            fast_gelu(acc[fm][n][4 * G + 3] + c3));
          *(int*)(Hout8 + (size_t)kt2 * hstride * 64 + packed_off(px, kc) + sub) = d;
        }
      }
    }
  } else {
    #pragma unroll
    for (int fm = 0; fm < 2; ++fm) {
      const int wmf = wm * 2 + fm;
      #pragma unroll
      for (int G = 0; G < 4; ++G) {
        #pragma unroll
        for (int j = 0; j < 4; ++j) {
          const int c = arow0 + (wmf << 5) + 8 * G + 4 * kh + j;
          const float gv = gamma[c];
          const float bvv = bias[c];
          #pragma unroll
          for (int n = 0; n < 2; ++n) {
            const int px = px0 + brow0 + wn * 64 + n * 32 + lane31;
            const int bb = px >> 10, hw = px & 1023;
            const size_t oi = (((size_t)(bb * 384 + c)) << 10) + hw;
            out[oi] = xres[oi] + gv * (acc[fm][n][4 * G + j] + bvv);
          }
        }
      }
    }
  }
}

// ------------------------------- launcher ----------------------------------
extern "C" void kernel_launch(void* const* d_in, const int* in_sizes, int n_in,
                              void* d_out, int out_size, void* d_ws, size_t ws_size,
                              hipStream_t stream) {
  (void)in_sizes; (void)n_in; (void)out_size;
  const float* x     = (const float*)d_in[0];
  const float* pe_h  = (const float*)d_in[1];
  const float* w_h   = (const float*)d_in[2];
  const float* b_h   = (const float*)d_in[3];
  const float* pe_w  = (const float*)d_in[4];
  const float* w_w   = (const float*)d_in[5];
  const float* b_w   = (const float*)d_in[6];
  const float* ln_w  = (const float*)d_in[7];
  const float* ln_b  = (const float*)d_in[8];
  const float* w1    = (const float*)d_in[9];
  const float* b1    = (const float*)d_in[10];
  const float* w2    = (const float*)d_in[11];
  const float* b2    = (const float*)d_in[12];
  const float* gamma = (const float*)d_in[13];
  float* out = (float*)d_out;
  char* ws = (char*)d_ws;

  // ws: W1P [0, 0.59M) W2P [0.59M, 1.18M) YLNP [1.44M, 14.02M)
  //     CONV [14.02M, 39.19M) ; HID overlays CONV
  char*           W1P  = ws;
  char*           W2P  = ws + 589824;
  char*           YLNP = ws + 1441792;
  unsigned short* CONV = (unsigned short*)(ws + 14024704);
  char*           HID  = ws + 14024704;

  int G = 32;
  while (G > 2) {
    size_t hid = (size_t)G * 1572864ull;  // G*1024 px * 1536 B
    size_t need = 14024704ull + (hid > 25165824ull ? hid : 25165824ull);
    if (need <= ws_size) break;
    G -= 2;
  }

  constexpr int LDS1 = 256 * 64 * 3;  // 49152
  constexpr int LDS2 = 128 * 64 * 3;  // 24576

  prep_kernel<<<dim3(1596), dim3(256), 0, stream>>>(
      w1, w2, W1P, W2P, x, pe_h, w_h, b_h, pe_w, w_w, b_w, CONV);
  ln_fused_kernel<<<dim3(512), dim3(256), 0, stream>>>(CONV, YLNP, ln_w, ln_b);
  for (int i0 = 0; i0 < 32; i0 += G) {
    const int gi = (32 - i0 < G) ? (32 - i0) : G;
    const int Mpx = gi * 1024;
    // GEMM1: h-blocks 12 (nx), px-blocks Mpx/256. B = YLNP (kt-stride 32768 rows).
    {
      const int nwg = 12 * (Mpx / 256);
      gemm_kernel<0, 384, 1536, 4><<<dim3(nwg), dim3(512), LDS1, stream>>>(
          W1P, YLNP, HID, b1, nullptr, nullptr, nullptr,
          0, 32768, i0 * 1024, Mpx, nwg, 12);
    }
    // GEMM2: c-blocks 3 (nx), px-blocks Mpx/128. B = HID (kt-stride Mpx rows).
    {
      const int nwg = 3 * (Mpx / 128);
      gemm_kernel<1, 1536, 384, 2><<<dim3(nwg), dim3(256), LDS2, stream>>>(
          W2P, HID, nullptr, b2, gamma, x, out, i0 * 1024, Mpx, 0, 0, nwg, 3);
    }
  }
}

// Round 15
// 98.794 us; speedup vs baseline: 7.0165x; 7.0165x over previous
//
#include <hip/hip_runtime.h>

// ---------------------------------------------------------------------------
// ParC-ConvNeXt block, MI355X (gfx950).
//   out = x + gamma * MLP(LN(NHWC(concat(ParC_H(x[:192]), ParC_W(x[192:])))))
// Round 14 -> 15: FIX the round-14 spill. __launch_bounds__(.,6) capped
//   VGPRs at ~84 < the ~120 this kernel needs -> acc spilled to scratch
//   (VGPR=40, WRITE 1.2GB/dispatch, MfmaUtil 2%). Revert to (.,4) = 128-reg
//   cap. Structure otherwise identical to round 14: A (weights, L2-resident)
//   global->reg double-buffered, B-only LDS ring (NB=3, counted vmcnt),
//   wave tile 64x64 MX fp8, merged prep kernel.
// ---------------------------------------------------------------------------

typedef __attribute__((ext_vector_type(8))) short short8;
typedef __attribute__((ext_vector_type(4))) float f32x4;
typedef __attribute__((ext_vector_type(16))) float f32x16;
typedef __attribute__((ext_vector_type(4))) int int4v;
typedef __attribute__((ext_vector_type(8))) int i32x8;

__device__ __forceinline__ float bf2f(unsigned short u) {
  union { unsigned int i; float f; } v; v.i = ((unsigned int)u) << 16; return v.f;
}
__device__ __forceinline__ unsigned short f2bf(float f) {
  union { float f; unsigned int i; } v; v.f = f;
  unsigned int r = v.i + 0x7FFFu + ((v.i >> 16) & 1u);
  return (unsigned short)(r >> 16);
}

#if defined(__has_builtin)
#if __has_builtin(__builtin_amdgcn_global_load_lds)
#define HAS_GLL 1
#endif
#endif
#ifndef HAS_GLL
#define HAS_GLL 0
#endif

#if HAS_GLL
__device__ __forceinline__ void gload16(const void* g, void* l) {
  __builtin_amdgcn_global_load_lds((const __attribute__((address_space(1))) void*)g,
                                   (__attribute__((address_space(3))) void*)l, 16, 0, 0);
}
#else
__device__ __forceinline__ void gload16(const void* g, void* l) {
  *(f32x4*)l = *(const f32x4*)g;
}
#endif

template <int N>
__device__ __forceinline__ void wait_vm() {
  asm volatile("s_waitcnt vmcnt(%0)" :: "n"(N) : "memory");
}
__device__ __forceinline__ void barrier_raw() {
  __builtin_amdgcn_s_barrier();
  __builtin_amdgcn_sched_barrier(0);
}

// fast sigmoid-GELU: h * sigmoid(1.702h); exp2/rcp HW approx (1e-6 slack)
__device__ __forceinline__ float fast_gelu(float h) {
  const float e = __builtin_amdgcn_exp2f(-2.4554005f * h);  // 1.702/ln2 folded
  return h * __builtin_amdgcn_rcpf(1.f + e);
}

// pack 4 consecutive-k f32 into fp8 dword
__device__ __forceinline__ int pk4(float a, float b, float c, float d) {
  int r = __builtin_amdgcn_cvt_pk_fp8_f32(a, b, 0, false);
  return __builtin_amdgcn_cvt_pk_fp8_f32(c, d, r, true);
}

#define SCL1 0x7F7F7F7F  // E8M0 = 127 -> 2^0 in all 4 bytes

// Packed fragment layout (per kt): byte offset for (row, 16B-k-chunk kc):
//   (row>>5)*2048 + (kc&1)*1024 + (kc>>1)*512 + (row&31)*16
__device__ __forceinline__ int packed_off(int row, int kc) {
  return ((row >> 5) << 11) + ((kc & 1) << 10) + ((kc >> 1) << 9) + ((row & 31) << 4);
}

// --------------------- fused weight-pack + ParC conv -----------------------
// blocks 0..35:  w1 -> W1P [kt 6][packed h 1536];  36..59: w2 -> W2P [kt 24]
// blocks 60..1595: ParC conv (bid-60), writes CONV bf16 NCHW.
__global__ __launch_bounds__(256) void prep_kernel(
    const float* __restrict__ w1, const float* __restrict__ w2,
    char* __restrict__ w1p, char* __restrict__ w2p,
    const float* __restrict__ x,
    const float* __restrict__ pe_h, const float* __restrict__ w_h, const float* __restrict__ b_h,
    const float* __restrict__ pe_w, const float* __restrict__ w_w, const float* __restrict__ b_w,
    unsigned short* __restrict__ convout) {
  const int t = threadIdx.x;
  int bid = blockIdx.x;
  if (bid < 60) {
    float v[64];
    if (bid < 36) {
      const int kt = bid % 6, hg = bid / 6;
      const int h = hg * 256 + t;
      #pragma unroll
      for (int k = 0; k < 64; ++k) v[k] = w1[(size_t)(kt * 64 + k) * 1536 + h];
      char* base = w1p + (size_t)kt * 1536 * 64;
      #pragma unroll
      for (int k0 = 0; k0 < 64; k0 += 4)
        *(int*)(base + packed_off(h, k0 >> 4) + (k0 & 12)) =
            pk4(v[k0], v[k0 + 1], v[k0 + 2], v[k0 + 3]);
    } else {
      const int kt = bid - 36;
      for (int c = t; c < 384; c += 256) {
        #pragma unroll
        for (int k = 0; k < 64; ++k) v[k] = w2[(size_t)(kt * 64 + k) * 384 + c];
        char* base = w2p + (size_t)kt * 384 * 64;
        #pragma unroll
        for (int k0 = 0; k0 < 64; k0 += 4)
          *(int*)(base + packed_off(c, k0 >> 4) + (k0 & 12)) =
              pk4(v[k0], v[k0 + 1], v[k0 + 2], v[k0 + 3]);
      }
    }
    return;
  }
  bid -= 60;
  __shared__ float wt_s[8][32], pe_s[8][32], pc_s[8][32];
  const int b = bid / 48, g = bid % 48;
  const int c0 = g << 3;
  const bool ish = (c0 < 192);
  const int cl = t >> 5, q = t & 31;
  {
    const int c = c0 + cl;
    if (ish) { wt_s[cl][q] = w_h[(c << 5) + q];           pe_s[cl][q] = pe_h[(c << 5) + q]; }
    else     { const int cc = c - 192;
               wt_s[cl][q] = w_w[(cc << 5) + q];          pe_s[cl][q] = pe_w[(cc << 5) + q]; }
  }
  __syncthreads();
  {
    float s = ish ? b_h[c0 + cl] : b_w[c0 + cl - 192];
    #pragma unroll
    for (int i = 0; i < 32; ++i) s += pe_s[cl][(q + i) & 31] * wt_s[cl][i];
    pc_s[cl][q] = s;
  }
  __syncthreads();
  const float* xp = x + ((size_t)(b * 384 + c0 + cl) << 10);
  float col[32];
  if (ish) {
    #pragma unroll
    for (int j = 0; j < 32; ++j) col[j] = xp[(j << 5) + q];
  } else {
    const float* rp = xp + (q << 5);
    #pragma unroll
    for (int j4 = 0; j4 < 8; ++j4) {
      f32x4 v = *(const f32x4*)&rp[j4 << 2];
      col[j4 * 4 + 0] = v[0]; col[j4 * 4 + 1] = v[1];
      col[j4 * 4 + 2] = v[2]; col[j4 * 4 + 3] = v[3];
    }
  }
  float wr[32];
  #pragma unroll
  for (int i = 0; i < 32; ++i) wr[i] = wt_s[cl][i];
  float o[32];
  #pragma unroll
  for (int oo = 0; oo < 32; ++oo) o[oo] = pc_s[cl][oo];
  #pragma unroll
  for (int i = 0; i < 32; ++i)
    #pragma unroll
    for (int oo = 0; oo < 32; ++oo)
      o[oo] = fmaf(col[(oo + i) & 31], wr[i], o[oo]);
  unsigned short* op = convout + ((size_t)(b * 384 + c0 + cl) << 10);
  if (ish) {
    #pragma unroll
    for (int oo = 0; oo < 32; ++oo) op[(oo << 5) + q] = f2bf(o[oo]);
  } else {
    #pragma unroll
    for (int j8 = 0; j8 < 4; ++j8) {
      short8 p;
      #pragma unroll
      for (int j = 0; j < 8; ++j) p[j] = (short)f2bf(o[j8 * 8 + j]);
      *(short8*)&op[(q << 5) + j8 * 8] = p;
    }
  }
}

// --------------------------- fused LayerNorm -------------------------------
__global__ __launch_bounds__(256) void ln_fused_kernel(
    const unsigned short* __restrict__ conv, char* __restrict__ ylnp,
    const float* __restrict__ ln_w, const float* __restrict__ ln_b) {
  __shared__ unsigned short tile[384][72];   // 55296 B (144B pitch, bank-safe)
  __shared__ float lws[384], lbs[384];
  __shared__ float ps[4][64], pq[4][64];
  __shared__ float mus[64], rss[64];
  const int t = threadIdx.x;
  const int pb = blockIdx.x;
  const int b = pb >> 4;
  const int hw0 = (pb & 15) << 6;
  for (int i = t; i < 384; i += 256) { lws[i] = ln_w[i]; lbs[i] = ln_b[i]; }
  #pragma unroll
  for (int i = 0; i < 12; ++i) {
    const int idx = t + i * 256;
    const int c = idx >> 3, j = idx & 7;
    short8 v = *(const short8*)(conv + (((size_t)(b * 384 + c)) << 10) + hw0 + j * 8);
    *(short8*)&tile[c][j * 8] = v;
  }
  __syncthreads();
  {
    const int l = t & 63, qt = t >> 6;
    float s = 0.f, ss = 0.f;
    #pragma unroll
    for (int k = 0; k < 96; ++k) {
      const float v = bf2f(tile[qt * 96 + k][l]);
      s += v; ss = fmaf(v, v, ss);
    }
    ps[qt][l] = s; pq[qt][l] = ss;
  }
  __syncthreads();
  if (t < 64) {
    const float st = ps[0][t] + ps[1][t] + ps[2][t] + ps[3][t];
    const float sq = pq[0][t] + pq[1][t] + pq[2][t] + pq[3][t];
    const float m = st * (1.f / 384.f);
    const float var = sq * (1.f / 384.f) - m * m;
    mus[t] = m; rss[t] = rsqrtf(var + 1e-6f);
  }
  __syncthreads();
  const int l = t & 63, kc = t >> 6;
  const int px = pb * 64 + l;
  const float m = mus[l], r = rss[l];
  #pragma unroll
  for (int kt = 0; kt < 6; ++kt) {
    const int c0 = kt * 64 + kc * 16;
    float ov[16];
    #pragma unroll
    for (int e = 0; e < 16; ++e) {
      const float v = bf2f(tile[c0 + e][l]);
      ov[e] = (v - m) * r * lws[c0 + e] + lbs[c0 + e];
    }
    int4v d;
    d[0] = pk4(ov[0],  ov[1],  ov[2],  ov[3]);
    d[1] = pk4(ov[4],  ov[5],  ov[6],  ov[7]);
    d[2] = pk4(ov[8],  ov[9],  ov[10], ov[11]);
    d[3] = pk4(ov[12], ov[13], ov[14], ov[15]);
    *(int4v*)(ylnp + (size_t)kt * 32768 * 64 + packed_off(px, kc)) = d;
  }
}

// --------------------------- GEMM (MX fp8) ---------------------------------
// A (weights) from global/L2 -> registers (1-step reg double-buffer);
// B (activations) via gload_lds ring (NB=3, counted vmcnt).
// Wave tile 64x64 (acc f32x16[2][2]); NWM=2 x NWN waves; BM=128, BN=NWN*64.
// Per step per wave: 4 global A loads + 4 ds_read_b128 (R=1) + 4 MFMA.
// __launch_bounds__(.,4): 128-VGPR cap >= ~122 live (6 spilled acc -- r14).
// EPI 0 (GEMM1, NWN=4): HID fp8 [kt 24][packed px hstride], gelu+pk4.
// EPI 1 (GEMM2, NWN=2): out(NCHW f32) = x + gamma*(acc+b2).
template <int EPI, int KDIM, int AROWS, int NWN>
__global__ __launch_bounds__(NWN * 128, 4) void gemm_kernel(
    const char* __restrict__ Ab, const char* __restrict__ Bb,
    char* __restrict__ Hout8, const float* __restrict__ bias,
    const float* __restrict__ gamma, const float* __restrict__ xres,
    float* __restrict__ out, int px0, int bstride, int boff, int hstride,
    int nwg, int nx) {
  extern __shared__ char lds[];
  constexpr int BM = 128;
  constexpr int BN = NWN * 64;
  constexpr int THREADS = NWN * 128;
  constexpr int NB = 3;
  constexpr int NT = KDIM / 64;
  constexpr int SLOT = BN * 64;
  constexpr int BCH = BN * 4 / THREADS;      // = 2 for both configs
  static_assert(BCH == 2, "vmcnt schedule assumes 2 B-ops/thread");
  const int tid = threadIdx.x;
  const int lane = tid & 63;
  const int wid = tid >> 6;
  const int wm = wid / NWN;                  // 0..1: A 64-row half
  const int wn = wid % NWN;                  // B 64-px group
  const int lane31 = lane & 31;
  const int kh = lane >> 5;
  const int bid = blockIdx.x;
  const int q = nwg >> 3, r = nwg & 7;
  const int xcd = bid & 7, idx = bid >> 3;
  const int lg = (xcd < r ? xcd * (q + 1) : r * (q + 1) + (xcd - r) * q) + idx;
  const int xb = lg % nx, yb = lg / nx;
  const int arow0 = xb * BM;
  const int brow0 = yb * BN;

  f32x16 acc[2][2] = {};

  // per-thread A global base (weights, packed layout; frags at +0/1024/2048/3072)
  const char* aglob = Ab + ((size_t)(arow0 + wm * 64)) * 64 + (kh << 9) + (lane31 << 4);
  int bbase[2];
  #pragma unroll
  for (int n = 0; n < 2; ++n)
    bbase[n] = ((wn * 2 + n) << 11) + (kh << 9) + (lane31 << 4);

  auto stageB = [&](int tile) {
    char* sl = lds + (tile % NB) * SLOT;
    const char* bsrc = Bb + ((size_t)tile * bstride + boff + brow0) * 64;
    #pragma unroll
    for (int i = 0; i < BCH; ++i)
      gload16(bsrc + (i * THREADS + tid) * 16, sl + (i * THREADS + tid) * 16);
  };
  auto loadA = [&](int t, i32x8& f0, i32x8& f1) {
    const char* p = aglob + (size_t)t * (size_t)(AROWS * 64);
    int4v q0 = *(const int4v*)(p);
    int4v q1 = *(const int4v*)(p + 1024);
    int4v q2 = *(const int4v*)(p + 2048);
    int4v q3 = *(const int4v*)(p + 3072);
    f0[0]=q0[0]; f0[1]=q0[1]; f0[2]=q0[2]; f0[3]=q0[3];
    f0[4]=q1[0]; f0[5]=q1[1]; f0[6]=q1[2]; f0[7]=q1[3];
    f1[0]=q2[0]; f1[1]=q2[1]; f1[2]=q2[2]; f1[3]=q2[3];
    f1[4]=q3[0]; f1[5]=q3[1]; f1[6]=q3[2]; f1[7]=q3[3];
  };
  auto readB = [&](int t, i32x8 bv[2]) {
    const char* slp = lds + (t % NB) * SLOT;
    #pragma unroll
    for (int n = 0; n < 2; ++n) {
      int4v p0 = *(const int4v*)(slp + bbase[n]);
      int4v p1 = *(const int4v*)(slp + bbase[n] + 1024);
      bv[n][0]=p0[0]; bv[n][1]=p0[1]; bv[n][2]=p0[2]; bv[n][3]=p0[3];
      bv[n][4]=p1[0]; bv[n][5]=p1[1]; bv[n][6]=p1[2]; bv[n][7]=p1[3];
    }
  };
  auto mfma4 = [&](i32x8& a0, i32x8& a1, i32x8 bv[2]) {
    __builtin_amdgcn_s_setprio(1);
    acc[0][0] = __builtin_amdgcn_mfma_scale_f32_32x32x64_f8f6f4(
        a0, bv[0], acc[0][0], 0, 0, 0, SCL1, 0, SCL1);
    acc[0][1] = __builtin_amdgcn_mfma_scale_f32_32x32x64_f8f6f4(
        a0, bv[1], acc[0][1], 0, 0, 0, SCL1, 0, SCL1);
    acc[1][0] = __builtin_amdgcn_mfma_scale_f32_32x32x64_f8f6f4(
        a1, bv[0], acc[1][0], 0, 0, 0, SCL1, 0, SCL1);
    acc[1][1] = __builtin_amdgcn_mfma_scale_f32_32x32x64_f8f6f4(
        a1, bv[1], acc[1][1], 0, 0, 0, SCL1, 0, SCL1);
    __builtin_amdgcn_s_setprio(0);
  };

  i32x8 aA0, aA1, aB0, aB1;
  // prologue: A(0) first, then B(0), B(1) -> wait vmcnt(2) leaves B(1) in flight
  loadA(0, aA0, aA1);
  stageB(0);
  stageB(1);
  wait_vm<2>();
  barrier_raw();

  int t = 0;
  #pragma unroll 1
  for (; t + 3 < NT; t += 2) {
    {
      i32x8 bv[2]; readB(t, bv);
      loadA(t + 1, aB0, aB1);
      stageB(t + 2);
      mfma4(aA0, aA1, bv);
      wait_vm<2>();           // A(t+1) + B(t+1) landed; B(t+2) in flight
      barrier_raw();
    }
    {
      i32x8 bv[2]; readB(t + 1, bv);
      loadA(t + 2, aA0, aA1);
      stageB(t + 3);
      mfma4(aB0, aB1, bv);
      wait_vm<2>();
      barrier_raw();
    }
  }
  // peeled final pair (t == NT-2)
  {
    i32x8 bv[2]; readB(t, bv);
    loadA(t + 1, aB0, aB1);
    mfma4(aA0, aA1, bv);
    wait_vm<0>();
    barrier_raw();
  }
  {
    i32x8 bv[2]; readB(t + 1, bv);
    mfma4(aB0, aB1, bv);
  }

  // D (32x32 frag): col = lane31, row = (reg&3) + 8*(reg>>2) + 4*kh
  if (EPI == 0) {
    #pragma unroll
    for (int fm = 0; fm < 2; ++fm) {
      const int wmf = wm * 2 + fm;
      const int kt2 = (arow0 >> 6) + (wmf >> 1);
      #pragma unroll
      for (int G = 0; G < 4; ++G) {
        const int hbyte = ((wmf & 1) << 5) + 8 * G + 4 * kh;
        const int hglob = arow0 + (wmf << 5) + 8 * G + 4 * kh;
        const float c0 = bias[hglob + 0], c1 = bias[hglob + 1];
        const float c2 = bias[hglob + 2], c3 = bias[hglob + 3];
        const int kc = hbyte >> 4, sub = hbyte & 15;
        #pragma unroll
        for (int n = 0; n < 2; ++n) {
          const int px = brow0 + wn * 64 + n * 32 + lane31;
          const int d = pk4(fast_gelu(acc[fm][n][4 * G + 0] + c0),
                            fast_gelu(acc[fm][n][4 * G + 1] + c1),
                            fast_gelu(acc[fm][n][4 * G + 2] + c2),
                            fast_gelu(acc[fm][n][4 * G + 3] + c3));
          *(int*)(Hout8 + (size_t)kt2 * hstride * 64 + packed_off(px, kc) + sub) = d;
        }
      }
    }
  } else {
    #pragma unroll
    for (int fm = 0; fm < 2; ++fm) {
      const int wmf = wm * 2 + fm;
      #pragma unroll
      for (int G = 0; G < 4; ++G) {
        #pragma unroll
        for (int j = 0; j < 4; ++j) {
          const int c = arow0 + (wmf << 5) + 8 * G + 4 * kh + j;
          const float gv = gamma[c];
          const float bvv = bias[c];
          #pragma unroll
          for (int n = 0; n < 2; ++n) {
            const int px = px0 + brow0 + wn * 64 + n * 32 + lane31;
            const int bb = px >> 10, hw = px & 1023;
            const size_t oi = (((size_t)(bb * 384 + c)) << 10) + hw;
            out[oi] = xres[oi] + gv * (acc[fm][n][4 * G + j] + bvv);
          }
        }
      }
    }
  }
}

// ------------------------------- launcher ----------------------------------
extern "C" void kernel_launch(void* const* d_in, const int* in_sizes, int n_in,
                              void* d_out, int out_size, void* d_ws, size_t ws_size,
                              hipStream_t stream) {
  (void)in_sizes; (void)n_in; (void)out_size;
  const float* x     = (const float*)d_in[0];
  const float* pe_h  = (const float*)d_in[1];
  const float* w_h   = (const float*)d_in[2];
  const float* b_h   = (const float*)d_in[3];
  const float* pe_w  = (const float*)d_in[4];
  const float* w_w   = (const float*)d_in[5];
  const float* b_w   = (const float*)d_in[6];
  const float* ln_w  = (const float*)d_in[7];
  const float* ln_b  = (const float*)d_in[8];
  const float* w1    = (const float*)d_in[9];
  const float* b1    = (const float*)d_in[10];
  const float* w2    = (const float*)d_in[11];
  const float* b2    = (const float*)d_in[12];
  const float* gamma = (const float*)d_in[13];
  float* out = (float*)d_out;
  char* ws = (char*)d_ws;

  // ws: W1P [0, 0.59M) W2P [0.59M, 1.18M) YLNP [1.44M, 14.02M)
  //     CONV [14.02M, 39.19M) ; HID overlays CONV
  char*           W1P  = ws;
  char*           W2P  = ws + 589824;
  char*           YLNP = ws + 1441792;
  unsigned short* CONV = (unsigned short*)(ws + 14024704);
  char*           HID  = ws + 14024704;

  int G = 32;
  while (G > 2) {
    size_t hid = (size_t)G * 1572864ull;  // G*1024 px * 1536 B
    size_t need = 14024704ull + (hid > 25165824ull ? hid : 25165824ull);
    if (need <= ws_size) break;
    G -= 2;
  }

  constexpr int LDS1 = 256 * 64 * 3;  // 49152
  constexpr int LDS2 = 128 * 64 * 3;  // 24576

  prep_kernel<<<dim3(1596), dim3(256), 0, stream>>>(
      w1, w2, W1P, W2P, x, pe_h, w_h, b_h, pe_w, w_w, b_w, CONV);
  ln_fused_kernel<<<dim3(512), dim3(256), 0, stream>>>(CONV, YLNP, ln_w, ln_b);
  for (int i0 = 0; i0 < 32; i0 += G) {
    const int gi = (32 - i0 < G) ? (32 - i0) : G;
    const int Mpx = gi * 1024;
    // GEMM1: h-blocks 12 (nx), px-blocks Mpx/256. B = YLNP (kt-stride 32768 rows).
    {
      const int nwg = 12 * (Mpx / 256);
      gemm_kernel<0, 384, 1536, 4><<<dim3(nwg), dim3(512), LDS1, stream>>>(
          W1P, YLNP, HID, b1, nullptr, nullptr, nullptr,
          0, 32768, i0 * 1024, Mpx, nwg, 12);
    }
    // GEMM2: c-blocks 3 (nx), px-blocks Mpx/128. B = HID (kt-stride Mpx rows).
    {
      const int nwg = 3 * (Mpx / 128);
      gemm_kernel<1, 1536, 384, 2><<<dim3(nwg), dim3(256), LDS2, stream>>>(
          W2P, HID, nullptr, b2, gamma, x, out, i0 * 1024, Mpx, 0, 0, nwg, 3);
    }
  }
}

// Round 16
// 97.458 us; speedup vs baseline: 7.1127x; 1.0137x over previous
//
#include <hip/hip_runtime.h>

// ---------------------------------------------------------------------------
// ParC-ConvNeXt block, MI355X (gfx950).
//   out = x + gamma * MLP(LN(NHWC(concat(ParC_H(x[:192]), ParC_W(x[192:])))))
// Round 15 -> 16:
//   * GEMM1 rebuilt barrier-free: B panel (128px x K=384 fp8 = 48KB) staged
//     ENTIRELY in LDS in the prologue -> ONE barrier, k-loop has no barriers
//     or manual waitcnt (LDS read-only; A global->reg loads auto-scheduled
//     by compiler). 256 thr, 2x2 waves, 3 blocks/CU (49KB), unroll-3.
//   * __builtin_shufflevector builds i32x8 MFMA operands (kills ~48
//     v_mov/step) in both GEMMs.
//   * GEMM2 ring structure unchanged (B too big to full-stage).
// ---------------------------------------------------------------------------

typedef __attribute__((ext_vector_type(8))) short short8;
typedef __attribute__((ext_vector_type(4))) float f32x4;
typedef __attribute__((ext_vector_type(16))) float f32x16;
typedef __attribute__((ext_vector_type(4))) int int4v;
typedef __attribute__((ext_vector_type(8))) int i32x8;

__device__ __forceinline__ float bf2f(unsigned short u) {
  union { unsigned int i; float f; } v; v.i = ((unsigned int)u) << 16; return v.f;
}
__device__ __forceinline__ unsigned short f2bf(float f) {
  union { float f; unsigned int i; } v; v.f = f;
  unsigned int r = v.i + 0x7FFFu + ((v.i >> 16) & 1u);
  return (unsigned short)(r >> 16);
}
__device__ __forceinline__ i32x8 combine(int4v lo, int4v hi) {
  return __builtin_shufflevector(lo, hi, 0, 1, 2, 3, 4, 5, 6, 7);
}

#if defined(__has_builtin)
#if __has_builtin(__builtin_amdgcn_global_load_lds)
#define HAS_GLL 1
#endif
#endif
#ifndef HAS_GLL
#define HAS_GLL 0
#endif

#if HAS_GLL
__device__ __forceinline__ void gload16(const void* g, void* l) {
  __builtin_amdgcn_global_load_lds((const __attribute__((address_space(1))) void*)g,
                                   (__attribute__((address_space(3))) void*)l, 16, 0, 0);
}
#else
__device__ __forceinline__ void gload16(const void* g, void* l) {
  *(f32x4*)l = *(const f32x4*)g;
}
#endif

template <int N>
__device__ __forceinline__ void wait_vm() {
  asm volatile("s_waitcnt vmcnt(%0)" :: "n"(N) : "memory");
}
__device__ __forceinline__ void barrier_raw() {
  __builtin_amdgcn_s_barrier();
  __builtin_amdgcn_sched_barrier(0);
}

// fast sigmoid-GELU: h * sigmoid(1.702h); exp2/rcp HW approx (1e-6 slack)
__device__ __forceinline__ float fast_gelu(float h) {
  const float e = __builtin_amdgcn_exp2f(-2.4554005f * h);  // 1.702/ln2 folded
  return h * __builtin_amdgcn_rcpf(1.f + e);
}

// pack 4 consecutive-k f32 into fp8 dword
__device__ __forceinline__ int pk4(float a, float b, float c, float d) {
  int r = __builtin_amdgcn_cvt_pk_fp8_f32(a, b, 0, false);
  return __builtin_amdgcn_cvt_pk_fp8_f32(c, d, r, true);
}

#define SCL1 0x7F7F7F7F  // E8M0 = 127 -> 2^0 in all 4 bytes

// Packed fragment layout (per kt): byte offset for (row, 16B-k-chunk kc):
//   (row>>5)*2048 + (kc&1)*1024 + (kc>>1)*512 + (row&31)*16
__device__ __forceinline__ int packed_off(int row, int kc) {
  return ((row >> 5) << 11) + ((kc & 1) << 10) + ((kc >> 1) << 9) + ((row & 31) << 4);
}

// --------------------- fused weight-pack + ParC conv -----------------------
__global__ __launch_bounds__(256) void prep_kernel(
    const float* __restrict__ w1, const float* __restrict__ w2,
    char* __restrict__ w1p, char* __restrict__ w2p,
    const float* __restrict__ x,
    const float* __restrict__ pe_h, const float* __restrict__ w_h, const float* __restrict__ b_h,
    const float* __restrict__ pe_w, const float* __restrict__ w_w, const float* __restrict__ b_w,
    unsigned short* __restrict__ convout) {
  const int t = threadIdx.x;
  int bid = blockIdx.x;
  if (bid < 60) {
    float v[64];
    if (bid < 36) {
      const int kt = bid % 6, hg = bid / 6;
      const int h = hg * 256 + t;
      #pragma unroll
      for (int k = 0; k < 64; ++k) v[k] = w1[(size_t)(kt * 64 + k) * 1536 + h];
      char* base = w1p + (size_t)kt * 1536 * 64;
      #pragma unroll
      for (int k0 = 0; k0 < 64; k0 += 4)
        *(int*)(base + packed_off(h, k0 >> 4) + (k0 & 12)) =
            pk4(v[k0], v[k0 + 1], v[k0 + 2], v[k0 + 3]);
    } else {
      const int kt = bid - 36;
      for (int c = t; c < 384; c += 256) {
        #pragma unroll
        for (int k = 0; k < 64; ++k) v[k] = w2[(size_t)(kt * 64 + k) * 384 + c];
        char* base = w2p + (size_t)kt * 384 * 64;
        #pragma unroll
        for (int k0 = 0; k0 < 64; k0 += 4)
          *(int*)(base + packed_off(c, k0 >> 4) + (k0 & 12)) =
              pk4(v[k0], v[k0 + 1], v[k0 + 2], v[k0 + 3]);
      }
    }
    return;
  }
  bid -= 60;
  __shared__ float wt_s[8][32], pe_s[8][32], pc_s[8][32];
  const int b = bid / 48, g = bid % 48;
  const int c0 = g << 3;
  const bool ish = (c0 < 192);
  const int cl = t >> 5, q = t & 31;
  {
    const int c = c0 + cl;
    if (ish) { wt_s[cl][q] = w_h[(c << 5) + q];           pe_s[cl][q] = pe_h[(c << 5) + q]; }
    else     { const int cc = c - 192;
               wt_s[cl][q] = w_w[(cc << 5) + q];          pe_s[cl][q] = pe_w[(cc << 5) + q]; }
  }
  __syncthreads();
  {
    float s = ish ? b_h[c0 + cl] : b_w[c0 + cl - 192];
    #pragma unroll
    for (int i = 0; i < 32; ++i) s += pe_s[cl][(q + i) & 31] * wt_s[cl][i];
    pc_s[cl][q] = s;
  }
  __syncthreads();
  const float* xp = x + ((size_t)(b * 384 + c0 + cl) << 10);
  float col[32];
  if (ish) {
    #pragma unroll
    for (int j = 0; j < 32; ++j) col[j] = xp[(j << 5) + q];
  } else {
    const float* rp = xp + (q << 5);
    #pragma unroll
    for (int j4 = 0; j4 < 8; ++j4) {
      f32x4 v = *(const f32x4*)&rp[j4 << 2];
      col[j4 * 4 + 0] = v[0]; col[j4 * 4 + 1] = v[1];
      col[j4 * 4 + 2] = v[2]; col[j4 * 4 + 3] = v[3];
    }
  }
  float wr[32];
  #pragma unroll
  for (int i = 0; i < 32; ++i) wr[i] = wt_s[cl][i];
  float o[32];
  #pragma unroll
  for (int oo = 0; oo < 32; ++oo) o[oo] = pc_s[cl][oo];
  #pragma unroll
  for (int i = 0; i < 32; ++i)
    #pragma unroll
    for (int oo = 0; oo < 32; ++oo)
      o[oo] = fmaf(col[(oo + i) & 31], wr[i], o[oo]);
  unsigned short* op = convout + ((size_t)(b * 384 + c0 + cl) << 10);
  if (ish) {
    #pragma unroll
    for (int oo = 0; oo < 32; ++oo) op[(oo << 5) + q] = f2bf(o[oo]);
  } else {
    #pragma unroll
    for (int j8 = 0; j8 < 4; ++j8) {
      short8 p;
      #pragma unroll
      for (int j = 0; j < 8; ++j) p[j] = (short)f2bf(o[j8 * 8 + j]);
      *(short8*)&op[(q << 5) + j8 * 8] = p;
    }
  }
}

// --------------------------- fused LayerNorm -------------------------------
__global__ __launch_bounds__(256) void ln_fused_kernel(
    const unsigned short* __restrict__ conv, char* __restrict__ ylnp,
    const float* __restrict__ ln_w, const float* __restrict__ ln_b) {
  __shared__ unsigned short tile[384][72];   // 55296 B (144B pitch, bank-safe)
  __shared__ float lws[384], lbs[384];
  __shared__ float ps[4][64], pq[4][64];
  __shared__ float mus[64], rss[64];
  const int t = threadIdx.x;
  const int pb = blockIdx.x;
  const int b = pb >> 4;
  const int hw0 = (pb & 15) << 6;
  for (int i = t; i < 384; i += 256) { lws[i] = ln_w[i]; lbs[i] = ln_b[i]; }
  #pragma unroll
  for (int i = 0; i < 12; ++i) {
    const int idx = t + i * 256;
    const int c = idx >> 3, j = idx & 7;
    short8 v = *(const short8*)(conv + (((size_t)(b * 384 + c)) << 10) + hw0 + j * 8);
    *(short8*)&tile[c][j * 8] = v;
  }
  __syncthreads();
  {
    const int l = t & 63, qt = t >> 6;
    float s = 0.f, ss = 0.f;
    #pragma unroll
    for (int k = 0; k < 96; ++k) {
      const float v = bf2f(tile[qt * 96 + k][l]);
      s += v; ss = fmaf(v, v, ss);
    }
    ps[qt][l] = s; pq[qt][l] = ss;
  }
  __syncthreads();
  if (t < 64) {
    const float st = ps[0][t] + ps[1][t] + ps[2][t] + ps[3][t];
    const float sq = pq[0][t] + pq[1][t] + pq[2][t] + pq[3][t];
    const float m = st * (1.f / 384.f);
    const float var = sq * (1.f / 384.f) - m * m;
    mus[t] = m; rss[t] = rsqrtf(var + 1e-6f);
  }
  __syncthreads();
  const int l = t & 63, kc = t >> 6;
  const int px = pb * 64 + l;
  const float m = mus[l], r = rss[l];
  #pragma unroll
  for (int kt = 0; kt < 6; ++kt) {
    const int c0 = kt * 64 + kc * 16;
    float ov[16];
    #pragma unroll
    for (int e = 0; e < 16; ++e) {
      const float v = bf2f(tile[c0 + e][l]);
      ov[e] = (v - m) * r * lws[c0 + e] + lbs[c0 + e];
    }
    int4v d;
    d[0] = pk4(ov[0],  ov[1],  ov[2],  ov[3]);
    d[1] = pk4(ov[4],  ov[5],  ov[6],  ov[7]);
    d[2] = pk4(ov[8],  ov[9],  ov[10], ov[11]);
    d[3] = pk4(ov[12], ov[13], ov[14], ov[15]);
    *(int4v*)(ylnp + (size_t)kt * 32768 * 64 + packed_off(px, kc)) = d;
  }
}

// ----------------------- GEMM1 (MX fp8, barrier-free) ----------------------
// B panel (128 px x K=384) fully staged in LDS (48KB) in prologue; ONE
// barrier; k-loop has no syncs (LDS read-only, A loads compiler-scheduled).
// 256 thr = 4 waves 2x2; wave tile 64x64 (acc f32x16[2][2]). 3 blocks/CU.
template <int KDIM, int AROWS>
__global__ __launch_bounds__(256, 3) void gemm1_kernel(
    const char* __restrict__ Ab, const char* __restrict__ Bb,
    char* __restrict__ Hout8, const float* __restrict__ bias,
    int bstride, int boff, int hstride, int nwg, int nx) {
  extern __shared__ char lds[];
  constexpr int NT = KDIM / 64;              // 6
  const int tid = threadIdx.x;
  const int lane = tid & 63;
  const int wid = tid >> 6;
  const int wm = wid >> 1, wn = wid & 1;
  const int lane31 = lane & 31;
  const int kh = lane >> 5;
  const int bid = blockIdx.x;
  const int q = nwg >> 3, r = nwg & 7;
  const int xcd = bid & 7, idx = bid >> 3;
  const int lg = (xcd < r ? xcd * (q + 1) : r * (q + 1) + (xcd - r) * q) + idx;
  const int xb = lg % nx, yb = lg / nx;
  const int arow0 = xb * 128;
  const int brow0 = yb * 128;

  // stage ALL B tiles (identity copy, 2 ops/thread/tile)
  #pragma unroll
  for (int tt = 0; tt < NT; ++tt) {
    const char* bsrc = Bb + ((size_t)tt * bstride + boff + brow0) * 64;
    gload16(bsrc + tid * 16,          lds + tt * 8192 + tid * 16);
    gload16(bsrc + (256 + tid) * 16,  lds + tt * 8192 + (256 + tid) * 16);
  }
  const char* aglob = Ab + ((size_t)(arow0 + wm * 64)) * 64 + (kh << 9) + (lane31 << 4);
  const int bb0 = ((wn * 2 + 0) << 11) + (kh << 9) + (lane31 << 4);
  const int bb1 = ((wn * 2 + 1) << 11) + (kh << 9) + (lane31 << 4);
  wait_vm<0>();
  barrier_raw();

  f32x16 acc[2][2] = {};
  #pragma unroll 3
  for (int t = 0; t < NT; ++t) {
    const char* slp = lds + t * 8192;
    i32x8 bv0 = combine(*(const int4v*)(slp + bb0), *(const int4v*)(slp + bb0 + 1024));
    i32x8 bv1 = combine(*(const int4v*)(slp + bb1), *(const int4v*)(slp + bb1 + 1024));
    const char* p = aglob + (size_t)t * (size_t)(AROWS * 64);
    i32x8 a0 = combine(*(const int4v*)(p),        *(const int4v*)(p + 1024));
    i32x8 a1 = combine(*(const int4v*)(p + 2048), *(const int4v*)(p + 3072));
    __builtin_amdgcn_s_setprio(1);
    acc[0][0] = __builtin_amdgcn_mfma_scale_f32_32x32x64_f8f6f4(
        a0, bv0, acc[0][0], 0, 0, 0, SCL1, 0, SCL1);
    acc[0][1] = __builtin_amdgcn_mfma_scale_f32_32x32x64_f8f6f4(
        a0, bv1, acc[0][1], 0, 0, 0, SCL1, 0, SCL1);
    acc[1][0] = __builtin_amdgcn_mfma_scale_f32_32x32x64_f8f6f4(
        a1, bv0, acc[1][0], 0, 0, 0, SCL1, 0, SCL1);
    acc[1][1] = __builtin_amdgcn_mfma_scale_f32_32x32x64_f8f6f4(
        a1, bv1, acc[1][1], 0, 0, 0, SCL1, 0, SCL1);
    __builtin_amdgcn_s_setprio(0);
  }

  // D (32x32 frag): col = lane31, row = (reg&3) + 8*(reg>>2) + 4*kh
  #pragma unroll
  for (int fm = 0; fm < 2; ++fm) {
    const int wmf = wm * 2 + fm;
    const int kt2 = (arow0 >> 6) + (wmf >> 1);
    #pragma unroll
    for (int G = 0; G < 4; ++G) {
      const int hbyte = ((wmf & 1) << 5) + 8 * G + 4 * kh;
      const int hglob = arow0 + (wmf << 5) + 8 * G + 4 * kh;
      const float c0 = bias[hglob + 0], c1 = bias[hglob + 1];
      const float c2 = bias[hglob + 2], c3 = bias[hglob + 3];
      const int kc = hbyte >> 4, sub = hbyte & 15;
      #pragma unroll
      for (int n = 0; n < 2; ++n) {
        const int px = brow0 + wn * 64 + n * 32 + lane31;
        const int d = pk4(fast_gelu(acc[fm][n][4 * G + 0] + c0),
                          fast_gelu(acc[fm][n][4 * G + 1] + c1),
                          fast_gelu(acc[fm][n][4 * G + 2] + c2),
                          fast_gelu(acc[fm][n][4 * G + 3] + c3));
        *(int*)(Hout8 + (size_t)kt2 * hstride * 64 + packed_off(px, kc) + sub) = d;
      }
    }
  }
}

// ----------------------- GEMM2 (MX fp8, ring pipeline) ---------------------
// A (W2P, L2-resident) global->reg double-buffered; B (HID) LDS ring NB=3,
// counted vmcnt. 256 thr, 2x2 waves, wave tile 64x64. BM=BN=128.
template <int KDIM, int AROWS>
__global__ __launch_bounds__(256, 4) void gemm2_kernel(
    const char* __restrict__ Ab, const char* __restrict__ Bb,
    const float* __restrict__ bias, const float* __restrict__ gamma,
    const float* __restrict__ xres, float* __restrict__ out,
    int px0, int bstride, int boff, int nwg, int nx) {
  extern __shared__ char lds[];
  constexpr int NB = 3;
  constexpr int NT = KDIM / 64;
  constexpr int SLOT = 128 * 64;
  const int tid = threadIdx.x;
  const int lane = tid & 63;
  const int wid = tid >> 6;
  const int wm = wid >> 1, wn = wid & 1;
  const int lane31 = lane & 31;
  const int kh = lane >> 5;
  const int bid = blockIdx.x;
  const int q = nwg >> 3, r = nwg & 7;
  const int xcd = bid & 7, idx = bid >> 3;
  const int lg = (xcd < r ? xcd * (q + 1) : r * (q + 1) + (xcd - r) * q) + idx;
  const int xb = lg % nx, yb = lg / nx;
  const int arow0 = xb * 128;
  const int brow0 = yb * 128;

  f32x16 acc[2][2] = {};

  const char* aglob = Ab + ((size_t)(arow0 + wm * 64)) * 64 + (kh << 9) + (lane31 << 4);
  const int bb0 = ((wn * 2 + 0) << 11) + (kh << 9) + (lane31 << 4);
  const int bb1 = ((wn * 2 + 1) << 11) + (kh << 9) + (lane31 << 4);

  auto stageB = [&](int tile) {
    char* sl = lds + (tile % NB) * SLOT;
    const char* bsrc = Bb + ((size_t)tile * bstride + boff + brow0) * 64;
    gload16(bsrc + tid * 16,         sl + tid * 16);
    gload16(bsrc + (256 + tid) * 16, sl + (256 + tid) * 16);
  };
  auto loadA = [&](int t, i32x8& f0, i32x8& f1) {
    const char* p = aglob + (size_t)t * (size_t)(AROWS * 64);
    f0 = combine(*(const int4v*)(p),        *(const int4v*)(p + 1024));
    f1 = combine(*(const int4v*)(p + 2048), *(const int4v*)(p + 3072));
  };
  auto readB = [&](int t, i32x8& bv0, i32x8& bv1) {
    const char* slp = lds + (t % NB) * SLOT;
    bv0 = combine(*(const int4v*)(slp + bb0), *(const int4v*)(slp + bb0 + 1024));
    bv1 = combine(*(const int4v*)(slp + bb1), *(const int4v*)(slp + bb1 + 1024));
  };
  auto mfma4 = [&](i32x8& a0, i32x8& a1, i32x8& bv0, i32x8& bv1) {
    __builtin_amdgcn_s_setprio(1);
    acc[0][0] = __builtin_amdgcn_mfma_scale_f32_32x32x64_f8f6f4(
        a0, bv0, acc[0][0], 0, 0, 0, SCL1, 0, SCL1);
    acc[0][1] = __builtin_amdgcn_mfma_scale_f32_32x32x64_f8f6f4(
        a0, bv1, acc[0][1], 0, 0, 0, SCL1, 0, SCL1);
    acc[1][0] = __builtin_amdgcn_mfma_scale_f32_32x32x64_f8f6f4(
        a1, bv0, acc[1][0], 0, 0, 0, SCL1, 0, SCL1);
    acc[1][1] = __builtin_amdgcn_mfma_scale_f32_32x32x64_f8f6f4(
        a1, bv1, acc[1][1], 0, 0, 0, SCL1, 0, SCL1);
    __builtin_amdgcn_s_setprio(0);
  };

  i32x8 aA0, aA1, aB0, aB1;
  loadA(0, aA0, aA1);
  stageB(0);
  stageB(1);
  wait_vm<2>();
  barrier_raw();

  int t = 0;
  #pragma unroll 1
  for (; t + 3 < NT; t += 2) {
    {
      i32x8 bv0, bv1; readB(t, bv0, bv1);
      loadA(t + 1, aB0, aB1);
      stageB(t + 2);
      mfma4(aA0, aA1, bv0, bv1);
      wait_vm<2>();
      barrier_raw();
    }
    {
      i32x8 bv0, bv1; readB(t + 1, bv0, bv1);
      loadA(t + 2, aA0, aA1);
      stageB(t + 3);
      mfma4(aB0, aB1, bv0, bv1);
      wait_vm<2>();
      barrier_raw();
    }
  }
  {
    i32x8 bv0, bv1; readB(t, bv0, bv1);
    loadA(t + 1, aB0, aB1);
    mfma4(aA0, aA1, bv0, bv1);
    wait_vm<0>();
    barrier_raw();
  }
  {
    i32x8 bv0, bv1; readB(t + 1, bv0, bv1);
    mfma4(aB0, aB1, bv0, bv1);
  }

  #pragma unroll
  for (int fm = 0; fm < 2; ++fm) {
    const int wmf = wm * 2 + fm;
    #pragma unroll
    for (int G = 0; G < 4; ++G) {
      #pragma unroll
      for (int j = 0; j < 4; ++j) {
        const int c = arow0 + (wmf << 5) + 8 * G + 4 * kh + j;
        const float gv = gamma[c];
        const float bvv = bias[c];
        #pragma unroll
        for (int n = 0; n < 2; ++n) {
          const int px = px0 + brow0 + wn * 64 + n * 32 + lane31;
          const int bb = px >> 10, hw = px & 1023;
          const size_t oi = (((size_t)(bb * 384 + c)) << 10) + hw;
          out[oi] = xres[oi] + gv * (acc[fm][n][4 * G + j] + bvv);
        }
      }
    }
  }
}

// ------------------------------- launcher ----------------------------------
extern "C" void kernel_launch(void* const* d_in, const int* in_sizes, int n_in,
                              void* d_out, int out_size, void* d_ws, size_t ws_size,
                              hipStream_t stream) {
  (void)in_sizes; (void)n_in; (void)out_size;
  const float* x     = (const float*)d_in[0];
  const float* pe_h  = (const float*)d_in[1];
  const float* w_h   = (const float*)d_in[2];
  const float* b_h   = (const float*)d_in[3];
  const float* pe_w  = (const float*)d_in[4];
  const float* w_w   = (const float*)d_in[5];
  const float* b_w   = (const float*)d_in[6];
  const float* ln_w  = (const float*)d_in[7];
  const float* ln_b  = (const float*)d_in[8];
  const float* w1    = (const float*)d_in[9];
  const float* b1    = (const float*)d_in[10];
  const float* w2    = (const float*)d_in[11];
  const float* b2    = (const float*)d_in[12];
  const float* gamma = (const float*)d_in[13];
  float* out = (float*)d_out;
  char* ws = (char*)d_ws;

  // ws: W1P [0, 0.59M) W2P [0.59M, 1.18M) YLNP [1.44M, 14.02M)
  //     CONV [14.02M, 39.19M) ; HID overlays CONV
  char*           W1P  = ws;
  char*           W2P  = ws + 589824;
  char*           YLNP = ws + 1441792;
  unsigned short* CONV = (unsigned short*)(ws + 14024704);
  char*           HID  = ws + 14024704;

  int G = 32;
  while (G > 2) {
    size_t hid = (size_t)G * 1572864ull;  // G*1024 px * 1536 B
    size_t need = 14024704ull + (hid > 25165824ull ? hid : 25165824ull);
    if (need <= ws_size) break;
    G -= 2;
  }

  constexpr int LDS1 = 6 * 8192;      // 49152 (all K of B)
  constexpr int LDS2 = 128 * 64 * 3;  // 24576 (NB=3 ring)

  prep_kernel<<<dim3(1596), dim3(256), 0, stream>>>(
      w1, w2, W1P, W2P, x, pe_h, w_h, b_h, pe_w, w_w, b_w, CONV);
  ln_fused_kernel<<<dim3(512), dim3(256), 0, stream>>>(CONV, YLNP, ln_w, ln_b);
  for (int i0 = 0; i0 < 32; i0 += G) {
    const int gi = (32 - i0 < G) ? (32 - i0) : G;
    const int Mpx = gi * 1024;
    // GEMM1: h-blocks 12 (nx), px-blocks Mpx/128. B = YLNP (kt-stride 32768 rows).
    {
      const int nwg = 12 * (Mpx / 128);
      gemm1_kernel<384, 1536><<<dim3(nwg), dim3(256), LDS1, stream>>>(
          W1P, YLNP, HID, b1, 32768, i0 * 1024, Mpx, nwg, 12);
    }
    // GEMM2: c-blocks 3 (nx), px-blocks Mpx/128. B = HID (kt-stride Mpx rows).
    {
      const int nwg = 3 * (Mpx / 128);
      gemm2_kernel<1536, 384><<<dim3(nwg), dim3(256), LDS2, stream>>>(
          W2P, HID, b2, gamma, x, out, i0 * 1024, Mpx, 0, nwg, 3);
    }
  }
}

// Round 17
// 95.172 us; speedup vs baseline: 7.2835x; 1.0240x over previous
//
#include <hip/hip_runtime.h>

// ---------------------------------------------------------------------------
// ParC-ConvNeXt block, MI355X (gfx950).
//   out = x + gamma * MLP(LN(NHWC(concat(ParC_H(x[:192]), ParC_W(x[192:])))))
// Round 16 -> 17: FUSED MLP, take 2 (round-3 failure designed out: 3
//   barriers/block instead of 240; 72-MFMA barrier-free stretches).
//   Per 64-px block (512 thr, 8 waves, 120KB LDS):
//     stage YLN panel 24KB -> barrier
//     phase A: wave w computes h[192h][64px] (3x acc[2][2] K-loops; W1
//              L2->reg, B LDS read-only) -> gelu+pk4 -> h_lds (96KB packed)
//     lgkmcnt(0) + barrier
//     phase B: out[384c][64px] = W2(L2->reg) x h_lds; 3 frags/wave x 24 kt
//     epilogue: out = x + gamma*(acc+b2), px-contiguous.
//   HID tensor GONE (100MB HBM round-trip + one dispatch eliminated).
//   prep (pack+conv) and ln unchanged.
// ---------------------------------------------------------------------------

typedef __attribute__((ext_vector_type(8))) short short8;
typedef __attribute__((ext_vector_type(4))) float f32x4;
typedef __attribute__((ext_vector_type(16))) float f32x16;
typedef __attribute__((ext_vector_type(4))) int int4v;
typedef __attribute__((ext_vector_type(8))) int i32x8;

__device__ __forceinline__ float bf2f(unsigned short u) {
  union { unsigned int i; float f; } v; v.i = ((unsigned int)u) << 16; return v.f;
}
__device__ __forceinline__ unsigned short f2bf(float f) {
  union { float f; unsigned int i; } v; v.f = f;
  unsigned int r = v.i + 0x7FFFu + ((v.i >> 16) & 1u);
  return (unsigned short)(r >> 16);
}
__device__ __forceinline__ i32x8 combine(int4v lo, int4v hi) {
  return __builtin_shufflevector(lo, hi, 0, 1, 2, 3, 4, 5, 6, 7);
}
__device__ __forceinline__ int4v ld16(const char* p) { return *(const int4v*)p; }

#if defined(__has_builtin)
#if __has_builtin(__builtin_amdgcn_global_load_lds)
#define HAS_GLL 1
#endif
#endif
#ifndef HAS_GLL
#define HAS_GLL 0
#endif

#if HAS_GLL
__device__ __forceinline__ void gload16(const void* g, void* l) {
  __builtin_amdgcn_global_load_lds((const __attribute__((address_space(1))) void*)g,
                                   (__attribute__((address_space(3))) void*)l, 16, 0, 0);
}
#else
__device__ __forceinline__ void gload16(const void* g, void* l) {
  *(f32x4*)l = *(const f32x4*)g;
}
#endif

template <int N>
__device__ __forceinline__ void wait_vm() {
  asm volatile("s_waitcnt vmcnt(%0)" :: "n"(N) : "memory");
}
__device__ __forceinline__ void barrier_raw() {
  __builtin_amdgcn_s_barrier();
  __builtin_amdgcn_sched_barrier(0);
}

// fast sigmoid-GELU: h * sigmoid(1.702h); exp2/rcp HW approx (1e-6 slack)
__device__ __forceinline__ float fast_gelu(float h) {
  const float e = __builtin_amdgcn_exp2f(-2.4554005f * h);  // 1.702/ln2 folded
  return h * __builtin_amdgcn_rcpf(1.f + e);
}

// pack 4 consecutive-k f32 into fp8 dword
__device__ __forceinline__ int pk4(float a, float b, float c, float d) {
  int r = __builtin_amdgcn_cvt_pk_fp8_f32(a, b, 0, false);
  return __builtin_amdgcn_cvt_pk_fp8_f32(c, d, r, true);
}

#define SCL1 0x7F7F7F7F  // E8M0 = 127 -> 2^0 in all 4 bytes

// Packed fragment layout (per kt): byte offset for (row, 16B-k-chunk kc):
//   (row>>5)*2048 + (kc&1)*1024 + (kc>>1)*512 + (row&31)*16
__device__ __forceinline__ int packed_off(int row, int kc) {
  return ((row >> 5) << 11) + ((kc & 1) << 10) + ((kc >> 1) << 9) + ((row & 31) << 4);
}

// --------------------- fused weight-pack + ParC conv -----------------------
__global__ __launch_bounds__(256) void prep_kernel(
    const float* __restrict__ w1, const float* __restrict__ w2,
    char* __restrict__ w1p, char* __restrict__ w2p,
    const float* __restrict__ x,
    const float* __restrict__ pe_h, const float* __restrict__ w_h, const float* __restrict__ b_h,
    const float* __restrict__ pe_w, const float* __restrict__ w_w, const float* __restrict__ b_w,
    unsigned short* __restrict__ convout) {
  const int t = threadIdx.x;
  int bid = blockIdx.x;
  if (bid < 60) {
    float v[64];
    if (bid < 36) {
      const int kt = bid % 6, hg = bid / 6;
      const int h = hg * 256 + t;
      #pragma unroll
      for (int k = 0; k < 64; ++k) v[k] = w1[(size_t)(kt * 64 + k) * 1536 + h];
      char* base = w1p + (size_t)kt * 1536 * 64;
      #pragma unroll
      for (int k0 = 0; k0 < 64; k0 += 4)
        *(int*)(base + packed_off(h, k0 >> 4) + (k0 & 12)) =
            pk4(v[k0], v[k0 + 1], v[k0 + 2], v[k0 + 3]);
    } else {
      const int kt = bid - 36;
      for (int c = t; c < 384; c += 256) {
        #pragma unroll
        for (int k = 0; k < 64; ++k) v[k] = w2[(size_t)(kt * 64 + k) * 384 + c];
        char* base = w2p + (size_t)kt * 384 * 64;
        #pragma unroll
        for (int k0 = 0; k0 < 64; k0 += 4)
          *(int*)(base + packed_off(c, k0 >> 4) + (k0 & 12)) =
              pk4(v[k0], v[k0 + 1], v[k0 + 2], v[k0 + 3]);
      }
    }
    return;
  }
  bid -= 60;
  __shared__ float wt_s[8][32], pe_s[8][32], pc_s[8][32];
  const int b = bid / 48, g = bid % 48;
  const int c0 = g << 3;
  const bool ish = (c0 < 192);
  const int cl = t >> 5, q = t & 31;
  {
    const int c = c0 + cl;
    if (ish) { wt_s[cl][q] = w_h[(c << 5) + q];           pe_s[cl][q] = pe_h[(c << 5) + q]; }
    else     { const int cc = c - 192;
               wt_s[cl][q] = w_w[(cc << 5) + q];          pe_s[cl][q] = pe_w[(cc << 5) + q]; }
  }
  __syncthreads();
  {
    float s = ish ? b_h[c0 + cl] : b_w[c0 + cl - 192];
    #pragma unroll
    for (int i = 0; i < 32; ++i) s += pe_s[cl][(q + i) & 31] * wt_s[cl][i];
    pc_s[cl][q] = s;
  }
  __syncthreads();
  const float* xp = x + ((size_t)(b * 384 + c0 + cl) << 10);
  float col[32];
  if (ish) {
    #pragma unroll
    for (int j = 0; j < 32; ++j) col[j] = xp[(j << 5) + q];
  } else {
    const float* rp = xp + (q << 5);
    #pragma unroll
    for (int j4 = 0; j4 < 8; ++j4) {
      f32x4 v = *(const f32x4*)&rp[j4 << 2];
      col[j4 * 4 + 0] = v[0]; col[j4 * 4 + 1] = v[1];
      col[j4 * 4 + 2] = v[2]; col[j4 * 4 + 3] = v[3];
    }
  }
  float wr[32];
  #pragma unroll
  for (int i = 0; i < 32; ++i) wr[i] = wt_s[cl][i];
  float o[32];
  #pragma unroll
  for (int oo = 0; oo < 32; ++oo) o[oo] = pc_s[cl][oo];
  #pragma unroll
  for (int i = 0; i < 32; ++i)
    #pragma unroll
    for (int oo = 0; oo < 32; ++oo)
      o[oo] = fmaf(col[(oo + i) & 31], wr[i], o[oo]);
  unsigned short* op = convout + ((size_t)(b * 384 + c0 + cl) << 10);
  if (ish) {
    #pragma unroll
    for (int oo = 0; oo < 32; ++oo) op[(oo << 5) + q] = f2bf(o[oo]);
  } else {
    #pragma unroll
    for (int j8 = 0; j8 < 4; ++j8) {
      short8 p;
      #pragma unroll
      for (int j = 0; j < 8; ++j) p[j] = (short)f2bf(o[j8 * 8 + j]);
      *(short8*)&op[(q << 5) + j8 * 8] = p;
    }
  }
}

// --------------------------- fused LayerNorm -------------------------------
__global__ __launch_bounds__(256) void ln_fused_kernel(
    const unsigned short* __restrict__ conv, char* __restrict__ ylnp,
    const float* __restrict__ ln_w, const float* __restrict__ ln_b) {
  __shared__ unsigned short tile[384][72];   // 55296 B (144B pitch, bank-safe)
  __shared__ float lws[384], lbs[384];
  __shared__ float ps[4][64], pq[4][64];
  __shared__ float mus[64], rss[64];
  const int t = threadIdx.x;
  const int pb = blockIdx.x;
  const int b = pb >> 4;
  const int hw0 = (pb & 15) << 6;
  for (int i = t; i < 384; i += 256) { lws[i] = ln_w[i]; lbs[i] = ln_b[i]; }
  #pragma unroll
  for (int i = 0; i < 12; ++i) {
    const int idx = t + i * 256;
    const int c = idx >> 3, j = idx & 7;
    short8 v = *(const short8*)(conv + (((size_t)(b * 384 + c)) << 10) + hw0 + j * 8);
    *(short8*)&tile[c][j * 8] = v;
  }
  __syncthreads();
  {
    const int l = t & 63, qt = t >> 6;
    float s = 0.f, ss = 0.f;
    #pragma unroll
    for (int k = 0; k < 96; ++k) {
      const float v = bf2f(tile[qt * 96 + k][l]);
      s += v; ss = fmaf(v, v, ss);
    }
    ps[qt][l] = s; pq[qt][l] = ss;
  }
  __syncthreads();
  if (t < 64) {
    const float st = ps[0][t] + ps[1][t] + ps[2][t] + ps[3][t];
    const float sq = pq[0][t] + pq[1][t] + pq[2][t] + pq[3][t];
    const float m = st * (1.f / 384.f);
    const float var = sq * (1.f / 384.f) - m * m;
    mus[t] = m; rss[t] = rsqrtf(var + 1e-6f);
  }
  __syncthreads();
  const int l = t & 63, kc = t >> 6;
  const int px = pb * 64 + l;
  const float m = mus[l], r = rss[l];
  #pragma unroll
  for (int kt = 0; kt < 6; ++kt) {
    const int c0 = kt * 64 + kc * 16;
    float ov[16];
    #pragma unroll
    for (int e = 0; e < 16; ++e) {
      const float v = bf2f(tile[c0 + e][l]);
      ov[e] = (v - m) * r * lws[c0 + e] + lbs[c0 + e];
    }
    int4v d;
    d[0] = pk4(ov[0],  ov[1],  ov[2],  ov[3]);
    d[1] = pk4(ov[4],  ov[5],  ov[6],  ov[7]);
    d[2] = pk4(ov[8],  ov[9],  ov[10], ov[11]);
    d[3] = pk4(ov[12], ov[13], ov[14], ov[15]);
    *(int4v*)(ylnp + (size_t)kt * 32768 * 64 + packed_off(px, kc)) = d;
  }
}

// ------------------------- fused MLP (MX fp8) -------------------------------
// One block = one 64-px strip. 512 thr = 8 waves. LDS: YLN panel 24KB +
// h 96KB (fragment-packed). 3 barriers total. Weights always L2->reg.
__global__ __launch_bounds__(512, 2) void fused_mlp_kernel(
    const char* __restrict__ W1P, const char* __restrict__ W2P,
    const char* __restrict__ YLNP,
    const float* __restrict__ b1, const float* __restrict__ b2,
    const float* __restrict__ gamma, const float* __restrict__ xres,
    float* __restrict__ out) {
  extern __shared__ char lds[];   // [0,24576): YLN; [24576,122880): h
  const int tid = threadIdx.x;
  const int lane = tid & 63;
  const int wid = tid >> 6;        // 0..7
  const int lane31 = lane & 31;
  const int kh = lane >> 5;
  const int px0 = blockIdx.x << 6;
  char* hl = lds + 24576;

  // ---- stage YLN panel: 6 kt x 4KB (64-px slice is contiguous in packed) --
  #pragma unroll
  for (int i = 0; i < 3; ++i) {
    const int idx = i * 512 + tid;          // 0..1535, 256 chunks/kt
    const int kt = idx >> 8;
    const int off = (idx & 255) << 4;
    gload16(YLNP + (size_t)kt * 2097152 + ((size_t)px0 << 6) + off,
            lds + kt * 4096 + off);
  }
  wait_vm<0>();
  barrier_raw();

  // ---- phase A: h[1536][64px]; wave w owns h rows [w*192, w*192+192) -----
  const int frkb = (kh << 9) + (lane31 << 4);
  #pragma unroll 1
  for (int sc = 0; sc < 3; ++sc) {
    const int hb = wid * 192 + sc * 64;
    const char* ag = W1P + (hb << 6) + frkb;
    f32x16 acc[2][2] = {};
    #pragma unroll
    for (int t = 0; t < 6; ++t) {
      const char* p = ag + (size_t)t * 98304;           // 1536*64 per kt
      i32x8 a0 = combine(ld16(p),        ld16(p + 1024));
      i32x8 a1 = combine(ld16(p + 2048), ld16(p + 3072));
      const char* bt = lds + t * 4096 + frkb;
      i32x8 bv0 = combine(ld16(bt),        ld16(bt + 1024));
      i32x8 bv1 = combine(ld16(bt + 2048), ld16(bt + 3072));
      __builtin_amdgcn_s_setprio(1);
      acc[0][0] = __builtin_amdgcn_mfma_scale_f32_32x32x64_f8f6f4(
          a0, bv0, acc[0][0], 0, 0, 0, SCL1, 0, SCL1);
      acc[0][1] = __builtin_amdgcn_mfma_scale_f32_32x32x64_f8f6f4(
          a0, bv1, acc[0][1], 0, 0, 0, SCL1, 0, SCL1);
      acc[1][0] = __builtin_amdgcn_mfma_scale_f32_32x32x64_f8f6f4(
          a1, bv0, acc[1][0], 0, 0, 0, SCL1, 0, SCL1);
      acc[1][1] = __builtin_amdgcn_mfma_scale_f32_32x32x64_f8f6f4(
          a1, bv1, acc[1][1], 0, 0, 0, SCL1, 0, SCL1);
      __builtin_amdgcn_s_setprio(0);
    }
    // GELU + pk4 -> h_lds (packed fragment layout, rows = local px)
    #pragma unroll
    for (int fm = 0; fm < 2; ++fm) {
      #pragma unroll
      for (int G = 0; G < 4; ++G) {
        const int h = hb + fm * 32 + 8 * G + 4 * kh;
        const float c0 = b1[h], c1 = b1[h + 1], c2 = b1[h + 2], c3 = b1[h + 3];
        const int kt2 = h >> 6;
        const int hbyte = h & 63;
        const int kc = hbyte >> 4, sub = hbyte & 15;
        #pragma unroll
        for (int n = 0; n < 2; ++n) {
          const int px = n * 32 + lane31;   // local
          const int d = pk4(fast_gelu(acc[fm][n][4 * G + 0] + c0),
                            fast_gelu(acc[fm][n][4 * G + 1] + c1),
                            fast_gelu(acc[fm][n][4 * G + 2] + c2),
                            fast_gelu(acc[fm][n][4 * G + 3] + c3));
          *(int*)(hl + kt2 * 4096 + packed_off(px, kc) + sub) = d;
        }
      }
    }
  }
  asm volatile("s_waitcnt lgkmcnt(0)" ::: "memory");
  barrier_raw();

  // ---- phase B: out[384c][64px]; wave w: px-frag (w&1), c-frags 3*(w>>1).. -
  const int pfrag = wid & 1;
  const int cg3 = (wid >> 1) * 3;          // first 32-c group of 3
  const char* ag2 = W2P + (cg3 << 11) + frkb;
  const int bboff = (pfrag << 11) + frkb;
  f32x16 acc0 = {}, acc1 = {}, acc2 = {};
  #pragma unroll 2
  for (int t = 0; t < 24; ++t) {
    const char* bt = hl + t * 4096 + bboff;
    i32x8 bv = combine(ld16(bt), ld16(bt + 1024));
    const char* p = ag2 + (size_t)t * 24576;            // 384*64 per kt
    i32x8 a0 = combine(ld16(p),        ld16(p + 1024));
    i32x8 a1 = combine(ld16(p + 2048), ld16(p + 3072));
    i32x8 a2 = combine(ld16(p + 4096), ld16(p + 5120));
    __builtin_amdgcn_s_setprio(1);
    acc0 = __builtin_amdgcn_mfma_scale_f32_32x32x64_f8f6f4(
        a0, bv, acc0, 0, 0, 0, SCL1, 0, SCL1);
    acc1 = __builtin_amdgcn_mfma_scale_f32_32x32x64_f8f6f4(
        a1, bv, acc1, 0, 0, 0, SCL1, 0, SCL1);
    acc2 = __builtin_amdgcn_mfma_scale_f32_32x32x64_f8f6f4(
        a2, bv, acc2, 0, 0, 0, SCL1, 0, SCL1);
    __builtin_amdgcn_s_setprio(0);
  }

  // ---- epilogue: out = x + gamma*(acc+b2), px-contiguous (128B/instr) -----
  const int px = px0 + pfrag * 32 + lane31;
  const int bb = px >> 10, hw = px & 1023;
  #pragma unroll
  for (int j = 0; j < 3; ++j) {
    const f32x16& aj = (j == 0) ? acc0 : (j == 1) ? acc1 : acc2;
    const int cbase = (cg3 + j) * 32;
    #pragma unroll
    for (int G = 0; G < 4; ++G) {
      #pragma unroll
      for (int jj = 0; jj < 4; ++jj) {
        const int c = cbase + 8 * G + 4 * kh + jj;
        const float gv = gamma[c];
        const float bvv = b2[c];
        const size_t oi = (((size_t)(bb * 384 + c)) << 10) + hw;
        out[oi] = xres[oi] + gv * (aj[4 * G + jj] + bvv);
      }
    }
  }
}

// ------------------------------- launcher ----------------------------------
extern "C" void kernel_launch(void* const* d_in, const int* in_sizes, int n_in,
                              void* d_out, int out_size, void* d_ws, size_t ws_size,
                              hipStream_t stream) {
  (void)in_sizes; (void)n_in; (void)out_size; (void)ws_size;
  const float* x     = (const float*)d_in[0];
  const float* pe_h  = (const float*)d_in[1];
  const float* w_h   = (const float*)d_in[2];
  const float* b_h   = (const float*)d_in[3];
  const float* pe_w  = (const float*)d_in[4];
  const float* w_w   = (const float*)d_in[5];
  const float* b_w   = (const float*)d_in[6];
  const float* ln_w  = (const float*)d_in[7];
  const float* ln_b  = (const float*)d_in[8];
  const float* w1    = (const float*)d_in[9];
  const float* b1    = (const float*)d_in[10];
  const float* w2    = (const float*)d_in[11];
  const float* b2    = (const float*)d_in[12];
  const float* gamma = (const float*)d_in[13];
  float* out = (float*)d_out;
  char* ws = (char*)d_ws;

  // ws: W1P [0, 0.59M) W2P [0.59M, 1.18M) YLNP [1.44M, 14.02M)
  //     CONV [14.02M, 39.19M)   (no HID anymore)
  char*           W1P  = ws;
  char*           W2P  = ws + 589824;
  char*           YLNP = ws + 1441792;
  unsigned short* CONV = (unsigned short*)(ws + 14024704);

  constexpr int LDSF = 24576 + 98304;  // 122880
  (void)hipFuncSetAttribute((const void*)fused_mlp_kernel,
                            hipFuncAttributeMaxDynamicSharedMemorySize, LDSF);

  prep_kernel<<<dim3(1596), dim3(256), 0, stream>>>(
      w1, w2, W1P, W2P, x, pe_h, w_h, b_h, pe_w, w_w, b_w, CONV);
  ln_fused_kernel<<<dim3(512), dim3(256), 0, stream>>>(CONV, YLNP, ln_w, ln_b);
  fused_mlp_kernel<<<dim3(512), dim3(512), LDSF, stream>>>(
      W1P, W2P, YLNP, b1, b2, gamma, x, out);
}